// Round 1
// baseline (725.479 us; speedup 1.0000x reference)
//
#include <hip/hip_runtime.h>
#include <float.h>

#define LSEQ 1024
#define NCH  8192   // B*H*d = 16*8*64
#define TOPK 13     // int(2*ln(1024))

// ---- Tiled transpose: in[b][r][c] -> out[b][c][r] -------------------------
__global__ __launch_bounds__(256) void transpose_rc(const float* __restrict__ in,
                                                    float* __restrict__ out,
                                                    int rows, int cols) {
  __shared__ float tile[32][33];
  int b  = blockIdx.z;
  int r0 = blockIdx.y * 32, c0 = blockIdx.x * 32;
  const float* src = in  + (size_t)b * rows * cols;
  float*       dst = out + (size_t)b * rows * cols;
  int tx = threadIdx.x, ty = threadIdx.y;   // block (32,8)
#pragma unroll
  for (int j = 0; j < 32; j += 8)
    tile[ty + j][tx] = src[(size_t)(r0 + ty + j) * cols + (c0 + tx)];
  __syncthreads();
#pragma unroll
  for (int j = 0; j < 32; j += 8)
    dst[(size_t)(c0 + ty + j) * rows + (r0 + tx)] = tile[tx][ty + j];
}

// ---- Direct circular correlation: corr[c][tau] = sum_s q[s]*k[(s-tau)%L] --
// One block per channel. Thread tid owns tau = 4*tid..4*tid+3.
// Rolling aligned 8-float k-window: 16 FMA per one lane-contiguous ds_read_b128.
__global__ __launch_bounds__(256) void corr_kernel(const float* __restrict__ qT,
                                                   const float* __restrict__ kT,
                                                   float* __restrict__ corr) {
  __shared__ float qs[LSEQ];
  __shared__ float k2[2 * LSEQ];
  int c   = blockIdx.x;
  int tid = threadIdx.x;
  {
    const float4* q4 = (const float4*)(qT + (size_t)c * LSEQ);
    const float4* k4 = (const float4*)(kT + (size_t)c * LSEQ);
    float4 qv = q4[tid];
    ((float4*)qs)[tid] = qv;
    float4 kv = k4[tid];
    ((float4*)k2)[tid]       = kv;   // k2[i]      = k[i]
    ((float4*)k2)[tid + 256] = kv;   // k2[i+1024] = k[i]
  }
  __syncthreads();
  const float4* qs4 = (const float4*)qs;
  const float4* k24 = (const float4*)k2;
  // tau0 = 4*tid ; base = 1024 - tau0 ; kb = base/4 = 256 - tid
  int kb = 256 - tid;
  float acc0 = 0.f, acc1 = 0.f, acc2 = 0.f, acc3 = 0.f;
  float4 lo = k24[kb - 1];           // k2[base-4 .. base-1]
#pragma unroll 4
  for (int s4 = 0; s4 < 256; ++s4) {
    float4 hi = k24[kb + s4];        // k2[s0+base .. s0+base+3]  (max idx 511: in bounds)
    float4 qv = qs4[s4];             // broadcast: same addr across lanes
    // acc[j] += q[s0+u] * k2[s0+u+base-j]  (window regs lo(4)+hi(4))
    acc0 += qv.x * hi.x; acc0 += qv.y * hi.y; acc0 += qv.z * hi.z; acc0 += qv.w * hi.w;
    acc1 += qv.x * lo.w; acc1 += qv.y * hi.x; acc1 += qv.z * hi.y; acc1 += qv.w * hi.z;
    acc2 += qv.x * lo.z; acc2 += qv.y * lo.w; acc2 += qv.z * hi.x; acc2 += qv.w * hi.y;
    acc3 += qv.x * lo.y; acc3 += qv.y * lo.z; acc3 += qv.z * lo.w; acc3 += qv.w * hi.x;
    lo = hi;
  }
  float4 r = make_float4(acc0, acc1, acc2, acc3);
  ((float4*)(corr + (size_t)c * LSEQ))[tid] = r;
}

// ---- Per-channel top-13 + softmax. One wave (64 lanes) per channel. -------
__global__ __launch_bounds__(256) void topk_kernel(const float* __restrict__ corr,
                                                   float* __restrict__ wout,
                                                   int* __restrict__ iout) {
  int wave = threadIdx.x >> 6;
  int lane = threadIdx.x & 63;
  int c = blockIdx.x * 4 + wave;
  const float* row = corr + (size_t)c * LSEQ;
  float v[16];
#pragma unroll
  for (int j = 0; j < 16; ++j) v[j] = row[lane + 64 * j];
  float topv[TOPK]; int topi[TOPK];
  for (int r = 0; r < TOPK; ++r) {
    float m = -FLT_MAX; int mi = 0x7fffffff;
#pragma unroll
    for (int j = 0; j < 16; ++j) {
      int idx = lane + 64 * j;
      if (v[j] > m || (v[j] == m && idx < mi)) { m = v[j]; mi = idx; }
    }
#pragma unroll
    for (int off = 32; off >= 1; off >>= 1) {
      float om = __shfl_xor(m, off);
      int   oi = __shfl_xor(mi, off);
      if (om > m || (om == m && oi < mi)) { m = om; mi = oi; }
    }
    topv[r] = m; topi[r] = mi;
    if (lane == (mi & 63)) v[mi >> 6] = -FLT_MAX;   // knock out the winner
  }
  // softmax over the 13 selected values (topv[0] is the global max)
  float mx = topv[0];
  float wv[TOPK]; float wsum = 0.f;
#pragma unroll
  for (int r = 0; r < TOPK; ++r) { wv[r] = __expf(topv[r] - mx); wsum += wv[r]; }
  float inv = 1.0f / wsum;
  if (lane == 0) {
#pragma unroll
    for (int r = 0; r < TOPK; ++r) {
      wout[(size_t)c * 16 + r] = wv[r] * inv;
      iout[(size_t)c * 16 + r] = topi[r];
    }
  }
}

// ---- Time-delay aggregation: outT[c][t] = sum_i w_i * v[min(idx_i+t,L-1)] -
__global__ __launch_bounds__(256) void agg_kernel(const float* __restrict__ vT,
                                                  const float* __restrict__ wbuf,
                                                  const int* __restrict__ ibuf,
                                                  float* __restrict__ outT) {
  __shared__ float v2[2 * LSEQ];     // clamped extension: v2[j>=1024] = v[1023]
  __shared__ float ws[TOPK];
  __shared__ int   is[TOPK];
  int c = blockIdx.x, tid = threadIdx.x;
  const float* v = vT + (size_t)c * LSEQ;
  float last = v[LSEQ - 1];
  float4 vv = ((const float4*)v)[tid];
  ((float4*)v2)[tid]       = vv;
  ((float4*)v2)[tid + 256] = make_float4(last, last, last, last);
  if (tid < TOPK) { ws[tid] = wbuf[(size_t)c * 16 + tid]; is[tid] = ibuf[(size_t)c * 16 + tid]; }
  __syncthreads();
  float a0 = 0.f, a1 = 0.f, a2 = 0.f, a3 = 0.f;
#pragma unroll
  for (int i = 0; i < TOPK; ++i) {
    float wi = ws[i]; int di = is[i];
    a0 += wi * v2[di + tid];
    a1 += wi * v2[di + tid + 256];
    a2 += wi * v2[di + tid + 512];
    a3 += wi * v2[di + tid + 768];
  }
  float* o = outT + (size_t)c * LSEQ + tid;
  o[0] = a0; o[256] = a1; o[512] = a2; o[768] = a3;
}

extern "C" void kernel_launch(void* const* d_in, const int* in_sizes, int n_in,
                              void* d_out, int out_size, void* d_ws, size_t ws_size,
                              hipStream_t stream) {
  const float* Q = (const float*)d_in[0];
  const float* K = (const float*)d_in[1];
  const float* V = (const float*)d_in[2];
  float* out = (float*)d_out;
  float* ws  = (float*)d_ws;
  // ws layout (floats): bufA[8192*1024] | bufB[8192*1024] | w[8192*16] | idx[8192*16]
  float* bufA = ws;
  float* bufB = ws + (size_t)NCH * LSEQ;
  float* wbuf = ws + (size_t)2 * NCH * LSEQ;
  int*   ibuf = (int*)(wbuf + (size_t)NCH * 16);
  float* corr = out;   // reuse d_out (32 MB) as corr scratch; fully rewritten at the end

  dim3 tb(32, 8);
  transpose_rc<<<dim3(16, 32, 16), tb, 0, stream>>>(Q, bufA, 1024, 512);  // qT
  transpose_rc<<<dim3(16, 32, 16), tb, 0, stream>>>(K, bufB, 1024, 512);  // kT
  corr_kernel<<<NCH, 256, 0, stream>>>(bufA, bufB, corr);
  topk_kernel<<<NCH / 4, 256, 0, stream>>>(corr, wbuf, ibuf);
  transpose_rc<<<dim3(16, 32, 16), tb, 0, stream>>>(V, bufA, 1024, 512);  // vT (qT dead)
  agg_kernel<<<NCH, 256, 0, stream>>>(bufA, wbuf, ibuf, bufB);            // outT (kT dead)
  transpose_rc<<<dim3(32, 16, 16), tb, 0, stream>>>(bufB, out, 512, 1024);
}

// Round 2
// 676.616 us; speedup vs baseline: 1.0722x; 1.0722x over previous
//
#include <hip/hip_runtime.h>
#include <float.h>

#define LSEQ 1024
#define NCH  8192   // B*H*d = 16*8*64
#define TOPK 13     // int(2*ln(1024))

// ---- Tiled transpose: in[b][r][c] -> out[b][c][r] -------------------------
__global__ __launch_bounds__(256) void transpose_rc(const float* __restrict__ in,
                                                    float* __restrict__ out,
                                                    int rows, int cols) {
  __shared__ float tile[32][33];
  int b  = blockIdx.z;
  int r0 = blockIdx.y * 32, c0 = blockIdx.x * 32;
  const float* src = in  + (size_t)b * rows * cols;
  float*       dst = out + (size_t)b * rows * cols;
  int tx = threadIdx.x, ty = threadIdx.y;   // block (32,8)
#pragma unroll
  for (int j = 0; j < 32; j += 8)
    tile[ty + j][tx] = src[(size_t)(r0 + ty + j) * cols + (c0 + tx)];
  __syncthreads();
#pragma unroll
  for (int j = 0; j < 32; j += 8)
    dst[(size_t)(c0 + ty + j) * rows + (r0 + tx)] = tile[tx][ty + j];
}

// ---- Direct circular correlation: corr[c][tau] = sum_s q[s]*k[(s-tau)%L] --
// One block per channel. Thread tid owns tau = 4*tid..4*tid+3.
// k staged in LDS (duplicated circular buffer), lane-contiguous ds_read_b128
// (conflict-free). q is WAVE-UNIFORM -> read straight from global so the
// compiler scalarizes it (s_load_dwordx4); FMAs take q from SGPRs, removing
// the broadcast ds_read_b128 that caused 1.7e8 bank-conflict cycles in R1.
__global__ __launch_bounds__(256) void corr_kernel(const float* __restrict__ qT,
                                                   const float* __restrict__ kT,
                                                   float* __restrict__ corr) {
  __shared__ float k2[2 * LSEQ];
  int c   = blockIdx.x;
  int tid = threadIdx.x;
  {
    const float4* k4 = (const float4*)(kT + (size_t)c * LSEQ);
    float4 kv = k4[tid];
    ((float4*)k2)[tid]       = kv;   // k2[i]      = k[i]
    ((float4*)k2)[tid + 256] = kv;   // k2[i+1024] = k[i]
  }
  __syncthreads();
  const float4* k24 = (const float4*)k2;
  const float4* q4  = (const float4*)(qT + (size_t)c * LSEQ);  // uniform row
  // tau0 = 4*tid ; base = 1024 - tau0 ; kb = base/4 = 256 - tid
  int kb = 256 - tid;
  float acc0 = 0.f, acc1 = 0.f, acc2 = 0.f, acc3 = 0.f;
  float4 lo = k24[kb - 1];           // k2[base-4 .. base-1]
#pragma unroll 16
  for (int s4 = 0; s4 < 256; ++s4) {
    float4 hi = k24[kb + s4];        // lane-contiguous 16B/lane: conflict-free
    float4 qv = q4[s4];              // uniform address -> s_load, SGPR operand
    // acc[j] += q[s0+u] * k2[s0+u+base-j]  (window regs lo(4)+hi(4))
    acc0 += qv.x * hi.x; acc0 += qv.y * hi.y; acc0 += qv.z * hi.z; acc0 += qv.w * hi.w;
    acc1 += qv.x * lo.w; acc1 += qv.y * hi.x; acc1 += qv.z * hi.y; acc1 += qv.w * hi.z;
    acc2 += qv.x * lo.z; acc2 += qv.y * lo.w; acc2 += qv.z * hi.x; acc2 += qv.w * hi.y;
    acc3 += qv.x * lo.y; acc3 += qv.y * lo.z; acc3 += qv.z * lo.w; acc3 += qv.w * hi.x;
    lo = hi;
  }
  float4 r = make_float4(acc0, acc1, acc2, acc3);
  ((float4*)(corr + (size_t)c * LSEQ))[tid] = r;
}

// ---- Per-channel top-13 + softmax. One wave (64 lanes) per channel. -------
__global__ __launch_bounds__(256) void topk_kernel(const float* __restrict__ corr,
                                                   float* __restrict__ wout,
                                                   int* __restrict__ iout) {
  int wave = threadIdx.x >> 6;
  int lane = threadIdx.x & 63;
  int c = blockIdx.x * 4 + wave;
  const float* row = corr + (size_t)c * LSEQ;
  float v[16];
#pragma unroll
  for (int j = 0; j < 16; ++j) v[j] = row[lane + 64 * j];
  float topv[TOPK]; int topi[TOPK];
  for (int r = 0; r < TOPK; ++r) {
    float m = -FLT_MAX; int mi = 0x7fffffff;
#pragma unroll
    for (int j = 0; j < 16; ++j) {
      int idx = lane + 64 * j;
      if (v[j] > m || (v[j] == m && idx < mi)) { m = v[j]; mi = idx; }
    }
#pragma unroll
    for (int off = 32; off >= 1; off >>= 1) {
      float om = __shfl_xor(m, off);
      int   oi = __shfl_xor(mi, off);
      if (om > m || (om == m && oi < mi)) { m = om; mi = oi; }
    }
    topv[r] = m; topi[r] = mi;
    if (lane == (mi & 63)) v[mi >> 6] = -FLT_MAX;   // knock out the winner
  }
  // softmax over the 13 selected values (topv[0] is the global max)
  float mx = topv[0];
  float wv[TOPK]; float wsum = 0.f;
#pragma unroll
  for (int r = 0; r < TOPK; ++r) { wv[r] = __expf(topv[r] - mx); wsum += wv[r]; }
  float inv = 1.0f / wsum;
  if (lane == 0) {
#pragma unroll
    for (int r = 0; r < TOPK; ++r) {
      wout[(size_t)c * 16 + r] = wv[r] * inv;
      iout[(size_t)c * 16 + r] = topi[r];
    }
  }
}

// ---- Time-delay aggregation: outT[c][t] = sum_i w_i * v[min(idx_i+t,L-1)] -
__global__ __launch_bounds__(256) void agg_kernel(const float* __restrict__ vT,
                                                  const float* __restrict__ wbuf,
                                                  const int* __restrict__ ibuf,
                                                  float* __restrict__ outT) {
  __shared__ float v2[2 * LSEQ];     // clamped extension: v2[j>=1024] = v[1023]
  __shared__ float ws[TOPK];
  __shared__ int   is[TOPK];
  int c = blockIdx.x, tid = threadIdx.x;
  const float* v = vT + (size_t)c * LSEQ;
  float last = v[LSEQ - 1];
  float4 vv = ((const float4*)v)[tid];
  ((float4*)v2)[tid]       = vv;
  ((float4*)v2)[tid + 256] = make_float4(last, last, last, last);
  if (tid < TOPK) { ws[tid] = wbuf[(size_t)c * 16 + tid]; is[tid] = ibuf[(size_t)c * 16 + tid]; }
  __syncthreads();
  float a0 = 0.f, a1 = 0.f, a2 = 0.f, a3 = 0.f;
#pragma unroll
  for (int i = 0; i < TOPK; ++i) {
    float wi = ws[i]; int di = is[i];
    a0 += wi * v2[di + tid];
    a1 += wi * v2[di + tid + 256];
    a2 += wi * v2[di + tid + 512];
    a3 += wi * v2[di + tid + 768];
  }
  float* o = outT + (size_t)c * LSEQ + tid;
  o[0] = a0; o[256] = a1; o[512] = a2; o[768] = a3;
}

extern "C" void kernel_launch(void* const* d_in, const int* in_sizes, int n_in,
                              void* d_out, int out_size, void* d_ws, size_t ws_size,
                              hipStream_t stream) {
  const float* Q = (const float*)d_in[0];
  const float* K = (const float*)d_in[1];
  const float* V = (const float*)d_in[2];
  float* out = (float*)d_out;
  float* ws  = (float*)d_ws;
  // ws layout (floats): bufA[8192*1024] | bufB[8192*1024] | w[8192*16] | idx[8192*16]
  float* bufA = ws;
  float* bufB = ws + (size_t)NCH * LSEQ;
  float* wbuf = ws + (size_t)2 * NCH * LSEQ;
  int*   ibuf = (int*)(wbuf + (size_t)NCH * 16);
  float* corr = out;   // reuse d_out (32 MB) as corr scratch; fully rewritten at the end

  dim3 tb(32, 8);
  transpose_rc<<<dim3(16, 32, 16), tb, 0, stream>>>(Q, bufA, 1024, 512);  // qT
  transpose_rc<<<dim3(16, 32, 16), tb, 0, stream>>>(K, bufB, 1024, 512);  // kT
  corr_kernel<<<NCH, 256, 0, stream>>>(bufA, bufB, corr);
  topk_kernel<<<NCH / 4, 256, 0, stream>>>(corr, wbuf, ibuf);
  transpose_rc<<<dim3(16, 32, 16), tb, 0, stream>>>(V, bufA, 1024, 512);  // vT (qT dead)
  agg_kernel<<<NCH, 256, 0, stream>>>(bufA, wbuf, ibuf, bufB);            // outT (kT dead)
  transpose_rc<<<dim3(32, 16, 16), tb, 0, stream>>>(bufB, out, 512, 1024);
}

// Round 3
// 672.348 us; speedup vs baseline: 1.0790x; 1.0063x over previous
//
#include <hip/hip_runtime.h>
#include <float.h>

#define LSEQ 1024
#define NCH  8192   // B*H*d = 16*8*64
#define TOPK 13     // int(2*ln(1024))

// ---- Tiled transpose: in[b][r][c] -> out[b][c][r] -------------------------
__global__ __launch_bounds__(256) void transpose_rc(const float* __restrict__ in,
                                                    float* __restrict__ out,
                                                    int rows, int cols) {
  __shared__ float tile[32][33];
  int b  = blockIdx.z;
  int r0 = blockIdx.y * 32, c0 = blockIdx.x * 32;
  const float* src = in  + (size_t)b * rows * cols;
  float*       dst = out + (size_t)b * rows * cols;
  int tx = threadIdx.x, ty = threadIdx.y;   // block (32,8)
#pragma unroll
  for (int j = 0; j < 32; j += 8)
    tile[ty + j][tx] = src[(size_t)(r0 + ty + j) * cols + (c0 + tx)];
  __syncthreads();
#pragma unroll
  for (int j = 0; j < 32; j += 8)
    dst[(size_t)(c0 + ty + j) * rows + (r0 + tx)] = tile[tx][ty + j];
}

// ---- Direct circular correlation: corr[c][tau] = sum_s q[s]*k[(s-tau)%L] --
// One block per channel. Thread tid owns tau0 = 4*(255-tid) (REVERSED so the
// LDS window read k24[tid+1+s4] is lane-ASCENDING contiguous — R2 showed the
// descending order (kb=256-tid) costs ~20 conflict-cyc per ds_read_b128;
// ascending is the m134 12-cyc fast path). q is wave-uniform -> scalar loads.
__global__ __launch_bounds__(256) void corr_kernel(const float* __restrict__ qT,
                                                   const float* __restrict__ kT,
                                                   float* __restrict__ corr) {
  __shared__ float k2[2 * LSEQ];
  int c   = blockIdx.x;
  int tid = threadIdx.x;
  {
    const float4* k4 = (const float4*)(kT + (size_t)c * LSEQ);
    float4 kv = k4[tid];
    ((float4*)k2)[tid]       = kv;   // k2[i]      = k[i]
    ((float4*)k2)[tid + 256] = kv;   // k2[i+1024] = k[i]
  }
  __syncthreads();
  const float4* k24 = (const float4*)k2;
  const float4* q4  = (const float4*)(qT + (size_t)c * LSEQ);  // uniform row
  // tau0 = 4*(255-tid) ; kb = (1024 - tau0)/4 = tid + 1
  int kb = tid + 1;
  float acc0 = 0.f, acc1 = 0.f, acc2 = 0.f, acc3 = 0.f;
  float4 lo = k24[kb - 1];           // = k24[tid], ascending in lane
#pragma unroll 16
  for (int s4 = 0; s4 < 256; ++s4) {
    float4 hi = k24[kb + s4];        // ascending lane-contiguous (max 511: ok)
    float4 qv = q4[s4];              // uniform address -> s_load, SGPR operand
    // acc[j] += q[4*s4+u] * k2[4*(kb+s4) + u - j]  (window regs lo(4)+hi(4))
    acc0 += qv.x * hi.x; acc0 += qv.y * hi.y; acc0 += qv.z * hi.z; acc0 += qv.w * hi.w;
    acc1 += qv.x * lo.w; acc1 += qv.y * hi.x; acc1 += qv.z * hi.y; acc1 += qv.w * hi.z;
    acc2 += qv.x * lo.z; acc2 += qv.y * lo.w; acc2 += qv.z * hi.x; acc2 += qv.w * hi.y;
    acc3 += qv.x * lo.y; acc3 += qv.y * lo.z; acc3 += qv.z * lo.w; acc3 += qv.w * hi.x;
    lo = hi;
  }
  float4 r = make_float4(acc0, acc1, acc2, acc3);
  ((float4*)(corr + (size_t)c * LSEQ))[255 - tid] = r;   // tau0/4 = 255 - tid
}

// ---- Per-channel top-13 + softmax. One wave (64 lanes) per channel. -------
__global__ __launch_bounds__(256) void topk_kernel(const float* __restrict__ corr,
                                                   float* __restrict__ wout,
                                                   int* __restrict__ iout) {
  int wave = threadIdx.x >> 6;
  int lane = threadIdx.x & 63;
  int c = blockIdx.x * 4 + wave;
  const float* row = corr + (size_t)c * LSEQ;
  float v[16];
#pragma unroll
  for (int j = 0; j < 16; ++j) v[j] = row[lane + 64 * j];
  float topv[TOPK]; int topi[TOPK];
  for (int r = 0; r < TOPK; ++r) {
    float m = -FLT_MAX; int mi = 0x7fffffff;
#pragma unroll
    for (int j = 0; j < 16; ++j) {
      int idx = lane + 64 * j;
      if (v[j] > m || (v[j] == m && idx < mi)) { m = v[j]; mi = idx; }
    }
#pragma unroll
    for (int off = 32; off >= 1; off >>= 1) {
      float om = __shfl_xor(m, off);
      int   oi = __shfl_xor(mi, off);
      if (om > m || (om == m && oi < mi)) { m = om; mi = oi; }
    }
    topv[r] = m; topi[r] = mi;
    if (lane == (mi & 63)) v[mi >> 6] = -FLT_MAX;   // knock out the winner
  }
  // softmax over the 13 selected values (topv[0] is the global max)
  float mx = topv[0];
  float wv[TOPK]; float wsum = 0.f;
#pragma unroll
  for (int r = 0; r < TOPK; ++r) { wv[r] = __expf(topv[r] - mx); wsum += wv[r]; }
  float inv = 1.0f / wsum;
  if (lane == 0) {
#pragma unroll
    for (int r = 0; r < TOPK; ++r) {
      wout[(size_t)c * 16 + r] = wv[r] * inv;
      iout[(size_t)c * 16 + r] = topi[r];
    }
  }
}

// ---- Time-delay aggregation: outT[c][t] = sum_i w_i * v[min(idx_i+t,L-1)] -
__global__ __launch_bounds__(256) void agg_kernel(const float* __restrict__ vT,
                                                  const float* __restrict__ wbuf,
                                                  const int* __restrict__ ibuf,
                                                  float* __restrict__ outT) {
  __shared__ float v2[2 * LSEQ];     // clamped extension: v2[j>=1024] = v[1023]
  __shared__ float ws[TOPK];
  __shared__ int   is[TOPK];
  int c = blockIdx.x, tid = threadIdx.x;
  const float* v = vT + (size_t)c * LSEQ;
  float last = v[LSEQ - 1];
  float4 vv = ((const float4*)v)[tid];
  ((float4*)v2)[tid]       = vv;
  ((float4*)v2)[tid + 256] = make_float4(last, last, last, last);
  if (tid < TOPK) { ws[tid] = wbuf[(size_t)c * 16 + tid]; is[tid] = ibuf[(size_t)c * 16 + tid]; }
  __syncthreads();
  float a0 = 0.f, a1 = 0.f, a2 = 0.f, a3 = 0.f;
#pragma unroll
  for (int i = 0; i < TOPK; ++i) {
    float wi = ws[i]; int di = is[i];
    a0 += wi * v2[di + tid];
    a1 += wi * v2[di + tid + 256];
    a2 += wi * v2[di + tid + 512];
    a3 += wi * v2[di + tid + 768];
  }
  float* o = outT + (size_t)c * LSEQ + tid;
  o[0] = a0; o[256] = a1; o[512] = a2; o[768] = a3;
}

extern "C" void kernel_launch(void* const* d_in, const int* in_sizes, int n_in,
                              void* d_out, int out_size, void* d_ws, size_t ws_size,
                              hipStream_t stream) {
  const float* Q = (const float*)d_in[0];
  const float* K = (const float*)d_in[1];
  const float* V = (const float*)d_in[2];
  float* out = (float*)d_out;
  float* ws  = (float*)d_ws;
  // ws layout (floats): bufA[8192*1024] | bufB[8192*1024] | w[8192*16] | idx[8192*16]
  float* bufA = ws;
  float* bufB = ws + (size_t)NCH * LSEQ;
  float* wbuf = ws + (size_t)2 * NCH * LSEQ;
  int*   ibuf = (int*)(wbuf + (size_t)NCH * 16);
  float* corr = out;   // reuse d_out (32 MB) as corr scratch; fully rewritten at the end

  dim3 tb(32, 8);
  transpose_rc<<<dim3(16, 32, 16), tb, 0, stream>>>(Q, bufA, 1024, 512);  // qT
  transpose_rc<<<dim3(16, 32, 16), tb, 0, stream>>>(K, bufB, 1024, 512);  // kT
  corr_kernel<<<NCH, 256, 0, stream>>>(bufA, bufB, corr);
  topk_kernel<<<NCH / 4, 256, 0, stream>>>(corr, wbuf, ibuf);
  transpose_rc<<<dim3(16, 32, 16), tb, 0, stream>>>(V, bufA, 1024, 512);  // vT (qT dead)
  agg_kernel<<<NCH, 256, 0, stream>>>(bufA, wbuf, ibuf, bufB);            // outT (kT dead)
  transpose_rc<<<dim3(32, 16, 16), tb, 0, stream>>>(bufB, out, 512, 1024);
}

// Round 4
// 438.303 us; speedup vs baseline: 1.6552x; 1.5340x over previous
//
#include <hip/hip_runtime.h>
#include <float.h>

#define LSEQ 1024
#define NCH  8192   // B*H*d = 16*8*64
#define TOPK 13     // int(2*ln(1024))
#define KPAD 1088   // 1024 + 1024/16 padding (addr(f) = f + (f>>4))

// ---- Tiled transpose: in[b][r][c] -> out[b][c][r] -------------------------
__global__ __launch_bounds__(256) void transpose_rc(const float* __restrict__ in,
                                                    float* __restrict__ out,
                                                    int rows, int cols) {
  __shared__ float tile[32][33];
  int b  = blockIdx.z;
  int r0 = blockIdx.y * 32, c0 = blockIdx.x * 32;
  const float* src = in  + (size_t)b * rows * cols;
  float*       dst = out + (size_t)b * rows * cols;
  int tx = threadIdx.x, ty = threadIdx.y;   // block (32,8)
#pragma unroll
  for (int j = 0; j < 32; j += 8)
    tile[ty + j][tx] = src[(size_t)(r0 + ty + j) * cols + (c0 + tx)];
  __syncthreads();
#pragma unroll
  for (int j = 0; j < 32; j += 8)
    dst[(size_t)(c0 + ty + j) * rows + (r0 + tx)] = tile[tx][ty + j];
}

// ---- Direct circular correlation: corr[c][tau] = sum_s q[s]*k[(s-tau)%L] --
// R3 evidence: ds_read_b128 is element-phased (4 phases x 8 banks) -> always
// 8-way conflicted (32 cyc). v4: one WAVE per channel, each lane owns 16
// CONSECUTIVE taus with a rolling 20-float register window -> 64 FMA per 16
// LDS bytes (4x fewer LDS instrs), fetched as 4x ds_read_b32 from a padded
// layout addr(f)=f+(f>>4): lane stride -17 dwords -> gcd(17,32)=1 -> 2-way
// (free). Circular wrap (&1023) jumps padded addr by 1088 = 0 mod 32: still
// conflict-free. q is wave-uniform -> scalar loads feed SGPR operands.
__global__ __launch_bounds__(256) void corr_kernel(const float* __restrict__ qT,
                                                   const float* __restrict__ kT,
                                                   float* __restrict__ corr) {
  __shared__ float kpad[4][KPAD];
  int wave = threadIdx.x >> 6, lane = threadIdx.x & 63;
  int c = blockIdx.x * 4 + wave;
  float* kp = kpad[wave];

  // Stage k into padded LDS. Own wave only -> no __syncthreads needed.
  {
    const float4* k4 = (const float4*)(kT + (size_t)c * LSEQ);
#pragma unroll
    for (int j = 0; j < 4; ++j) {
      int q = lane + 64 * j;          // quad index
      float4 kv = k4[q];
      int a = 4 * q + (q >> 2);       // padded addr of float 4q (no pad crossing in quad)
      kp[a] = kv.x; kp[a + 1] = kv.y; kp[a + 2] = kv.z; kp[a + 3] = kv.w;
    }
  }
  // Rolling window init: w[j] = k[(F + j) & 1023], F = 1008 - 16*lane
  int F = 1008 - 16 * lane;
  float w[20];
#pragma unroll
  for (int j = 0; j < 20; ++j) {
    int g = (F + j) & 1023;
    w[j] = kp[g + (g >> 4)];
  }
  float acc[16];
#pragma unroll
  for (int i = 0; i < 16; ++i) acc[i] = 0.f;

  const float4* q4 = (const float4*)(qT + (size_t)c * LSEQ);  // uniform -> s_load
#pragma unroll 4
  for (int t = 0; t < 256; ++t) {
    float4 qv = q4[t];
    // acc[i] (tau = 16*lane + i) += q[4t+u] * k[(4t+u - tau) & 1023] = w[16+u-i]
#pragma unroll
    for (int i = 0; i < 16; ++i) {
      acc[i] += qv.x * w[16 - i];
      acc[i] += qv.y * w[17 - i];
      acc[i] += qv.z * w[18 - i];
      acc[i] += qv.w * w[19 - i];
    }
    // advance window by 4 floats
#pragma unroll
    for (int j = 0; j < 16; ++j) w[j] = w[j + 4];
    int g0 = (F + 20 + 4 * t) & 1023;   // g0 % 4 == 0 -> quad shares one (g0>>4)
    int a0 = g0 + (g0 >> 4);
    w[16] = kp[a0]; w[17] = kp[a0 + 1]; w[18] = kp[a0 + 2]; w[19] = kp[a0 + 3];
  }

  float4* crow = (float4*)(corr + (size_t)c * LSEQ);
#pragma unroll
  for (int j = 0; j < 4; ++j)
    crow[lane * 4 + j] = make_float4(acc[4 * j], acc[4 * j + 1],
                                     acc[4 * j + 2], acc[4 * j + 3]);
}

// ---- Per-channel top-13 + softmax. One wave (64 lanes) per channel. -------
__global__ __launch_bounds__(256) void topk_kernel(const float* __restrict__ corr,
                                                   float* __restrict__ wout,
                                                   int* __restrict__ iout) {
  int wave = threadIdx.x >> 6;
  int lane = threadIdx.x & 63;
  int c = blockIdx.x * 4 + wave;
  const float* row = corr + (size_t)c * LSEQ;
  float v[16];
#pragma unroll
  for (int j = 0; j < 16; ++j) v[j] = row[lane + 64 * j];
  float topv[TOPK]; int topi[TOPK];
  for (int r = 0; r < TOPK; ++r) {
    float m = -FLT_MAX; int mi = 0x7fffffff;
#pragma unroll
    for (int j = 0; j < 16; ++j) {
      int idx = lane + 64 * j;
      if (v[j] > m || (v[j] == m && idx < mi)) { m = v[j]; mi = idx; }
    }
#pragma unroll
    for (int off = 32; off >= 1; off >>= 1) {
      float om = __shfl_xor(m, off);
      int   oi = __shfl_xor(mi, off);
      if (om > m || (om == m && oi < mi)) { m = om; mi = oi; }
    }
    topv[r] = m; topi[r] = mi;
    if (lane == (mi & 63)) v[mi >> 6] = -FLT_MAX;   // knock out the winner
  }
  // softmax over the 13 selected values (topv[0] is the global max)
  float mx = topv[0];
  float wv[TOPK]; float wsum = 0.f;
#pragma unroll
  for (int r = 0; r < TOPK; ++r) { wv[r] = __expf(topv[r] - mx); wsum += wv[r]; }
  float inv = 1.0f / wsum;
  if (lane == 0) {
#pragma unroll
    for (int r = 0; r < TOPK; ++r) {
      wout[(size_t)c * 16 + r] = wv[r] * inv;
      iout[(size_t)c * 16 + r] = topi[r];
    }
  }
}

// ---- Time-delay aggregation: outT[c][t] = sum_i w_i * v[min(idx_i+t,L-1)] -
__global__ __launch_bounds__(256) void agg_kernel(const float* __restrict__ vT,
                                                  const float* __restrict__ wbuf,
                                                  const int* __restrict__ ibuf,
                                                  float* __restrict__ outT) {
  __shared__ float v2[2 * LSEQ];     // clamped extension: v2[j>=1024] = v[1023]
  __shared__ float ws[TOPK];
  __shared__ int   is[TOPK];
  int c = blockIdx.x, tid = threadIdx.x;
  const float* v = vT + (size_t)c * LSEQ;
  float last = v[LSEQ - 1];
  float4 vv = ((const float4*)v)[tid];
  ((float4*)v2)[tid]       = vv;
  ((float4*)v2)[tid + 256] = make_float4(last, last, last, last);
  if (tid < TOPK) { ws[tid] = wbuf[(size_t)c * 16 + tid]; is[tid] = ibuf[(size_t)c * 16 + tid]; }
  __syncthreads();
  float a0 = 0.f, a1 = 0.f, a2 = 0.f, a3 = 0.f;
#pragma unroll
  for (int i = 0; i < TOPK; ++i) {
    float wi = ws[i]; int di = is[i];
    a0 += wi * v2[di + tid];
    a1 += wi * v2[di + tid + 256];
    a2 += wi * v2[di + tid + 512];
    a3 += wi * v2[di + tid + 768];
  }
  float* o = outT + (size_t)c * LSEQ + tid;
  o[0] = a0; o[256] = a1; o[512] = a2; o[768] = a3;
}

extern "C" void kernel_launch(void* const* d_in, const int* in_sizes, int n_in,
                              void* d_out, int out_size, void* d_ws, size_t ws_size,
                              hipStream_t stream) {
  const float* Q = (const float*)d_in[0];
  const float* K = (const float*)d_in[1];
  const float* V = (const float*)d_in[2];
  float* out = (float*)d_out;
  float* ws  = (float*)d_ws;
  // ws layout (floats): bufA[8192*1024] | bufB[8192*1024] | w[8192*16] | idx[8192*16]
  float* bufA = ws;
  float* bufB = ws + (size_t)NCH * LSEQ;
  float* wbuf = ws + (size_t)2 * NCH * LSEQ;
  int*   ibuf = (int*)(wbuf + (size_t)NCH * 16);
  float* corr = out;   // reuse d_out (32 MB) as corr scratch; fully rewritten at the end

  dim3 tb(32, 8);
  transpose_rc<<<dim3(16, 32, 16), tb, 0, stream>>>(Q, bufA, 1024, 512);  // qT
  transpose_rc<<<dim3(16, 32, 16), tb, 0, stream>>>(K, bufB, 1024, 512);  // kT
  corr_kernel<<<NCH / 4, 256, 0, stream>>>(bufA, bufB, corr);
  topk_kernel<<<NCH / 4, 256, 0, stream>>>(corr, wbuf, ibuf);
  transpose_rc<<<dim3(16, 32, 16), tb, 0, stream>>>(V, bufA, 1024, 512);  // vT (qT dead)
  agg_kernel<<<NCH, 256, 0, stream>>>(bufA, wbuf, ibuf, bufB);            // outT (kT dead)
  transpose_rc<<<dim3(32, 16, 16), tb, 0, stream>>>(bufB, out, 512, 1024);
}

// Round 5
// 410.392 us; speedup vs baseline: 1.7678x; 1.0680x over previous
//
#include <hip/hip_runtime.h>
#include <float.h>

#define LSEQ 1024
#define NCH  8192   // B*H*d = 16*8*64
#define TOPK 13     // int(2*ln(1024))
#define KPAD 1088   // 1024 + 1024/16 padding (addr(f) = f + (f>>4))

// ---- Tiled transpose: in[b][r][c] -> out[b][c][r] -------------------------
__global__ __launch_bounds__(256) void transpose_rc(const float* __restrict__ in,
                                                    float* __restrict__ out,
                                                    int rows, int cols) {
  __shared__ float tile[32][33];
  int b  = blockIdx.z;
  int r0 = blockIdx.y * 32, c0 = blockIdx.x * 32;
  const float* src = in  + (size_t)b * rows * cols;
  float*       dst = out + (size_t)b * rows * cols;
  int tx = threadIdx.x, ty = threadIdx.y;   // block (32,8)
#pragma unroll
  for (int j = 0; j < 32; j += 8)
    tile[ty + j][tx] = src[(size_t)(r0 + ty + j) * cols + (c0 + tx)];
  __syncthreads();
#pragma unroll
  for (int j = 0; j < 32; j += 8)
    dst[(size_t)(c0 + ty + j) * rows + (r0 + tx)] = tile[tx][ty + j];
}

// ---- Fused circular correlation + top-13 + softmax ------------------------
// corr[c][tau] = sum_s q[s]*k[(s-tau)%L]. One wave per channel; lane owns 16
// consecutive taus (tau = 16*lane+i). k staged in padded LDS (addr f+(f>>4):
// lane stride 17 dwords -> conflict-free b32, per R4 evidence). k window kept
// in a MOD-32 CIRCULAR register buffer; inner 8-phase loop fully unrolled so
// all cb[] indices are compile-time constants -> zero shift-movs (R4 spent
// 16 movs/iter). q is wave-uniform -> scalar loads. Top-k runs in-register
// right after accumulation (corr row never touches memory): butterfly argmax,
// knockout via predicated STATIC-indexed selects (dynamic index would spill
// acc[] to scratch and destroy the main loop).
__global__ __launch_bounds__(256) void corr_topk_kernel(const float* __restrict__ qT,
                                                        const float* __restrict__ kT,
                                                        float* __restrict__ wout,
                                                        int* __restrict__ iout) {
  __shared__ float kpad[4][KPAD];
  int wave = threadIdx.x >> 6, lane = threadIdx.x & 63;
  int c = blockIdx.x * 4 + wave;
  float* kp = kpad[wave];

  // Stage k into padded LDS. Own wave's data only -> no __syncthreads.
  {
    const float4* k4 = (const float4*)(kT + (size_t)c * LSEQ);
#pragma unroll
    for (int j = 0; j < 4; ++j) {
      int q = lane + 64 * j;          // quad index
      float4 kv = k4[q];
      int a = 4 * q + (q >> 2);       // padded addr (quad never crosses a pad)
      kp[a] = kv.x; kp[a + 1] = kv.y; kp[a + 2] = kv.z; kp[a + 3] = kv.w;
    }
  }
  // cb[(g + 4t) & 31] holds k[(F + g + 4t) & 1023]; F = 1008 - 16*lane.
  // Iter t needs g in [1,19]; we preload g = 0..19.
  int F = 1008 - 16 * lane;
  float cb[32];
#pragma unroll
  for (int g = 0; g < 20; ++g) {
    int gg = (F + g) & 1023;
    cb[g] = kp[gg + (gg >> 4)];
  }
  float acc[16];
#pragma unroll
  for (int i = 0; i < 16; ++i) acc[i] = 0.f;

  const float4* q4 = (const float4*)(qT + (size_t)c * LSEQ);  // uniform -> s_load
  for (int T = 0; T < 32; ++T) {
#pragma unroll
    for (int p = 0; p < 8; ++p) {     // phase: 4*8 = 32 = cb period -> static idx
      int t = T * 8 + p;
      float4 qv = q4[t];
#pragma unroll
      for (int i = 0; i < 16; ++i) {
        acc[i] += qv.x * cb[(4 * p + 16 - i) & 31];
        acc[i] += qv.y * cb[(4 * p + 17 - i) & 31];
        acc[i] += qv.z * cb[(4 * p + 18 - i) & 31];
        acc[i] += qv.w * cb[(4 * p + 19 - i) & 31];
      }
      int g0 = (F + 4 * t + 20) & 1023;   // %4==0 -> quad shares one (g0>>4)
      int a0 = g0 + (g0 >> 4);
      cb[(4 * p + 20) & 31] = kp[a0];
      cb[(4 * p + 21) & 31] = kp[a0 + 1];
      cb[(4 * p + 22) & 31] = kp[a0 + 2];
      cb[(4 * p + 23) & 31] = kp[a0 + 3];
    }
  }

  // ---- in-register top-13 (ties -> lowest index, matching lax.top_k) ----
  float topv[TOPK]; int topi[TOPK];
  for (int r = 0; r < TOPK; ++r) {
    float m = -FLT_MAX; int mi = 0x7fffffff;
#pragma unroll
    for (int j = 0; j < 16; ++j) {
      int idx = 16 * lane + j;
      if (acc[j] > m || (acc[j] == m && idx < mi)) { m = acc[j]; mi = idx; }
    }
#pragma unroll
    for (int off = 32; off >= 1; off >>= 1) {
      float om = __shfl_xor(m, off);
      int   oi = __shfl_xor(mi, off);
      if (om > m || (om == m && oi < mi)) { m = om; mi = oi; }
    }
    topv[r] = m; topi[r] = mi;
#pragma unroll
    for (int j = 0; j < 16; ++j)        // static-indexed knockout
      acc[j] = (16 * lane + j == mi) ? -FLT_MAX : acc[j];
  }
  float mx = topv[0];
  float wv[TOPK]; float wsum = 0.f;
#pragma unroll
  for (int r = 0; r < TOPK; ++r) { wv[r] = __expf(topv[r] - mx); wsum += wv[r]; }
  float inv = 1.0f / wsum;
  if (lane == 0) {
#pragma unroll
    for (int r = 0; r < TOPK; ++r) {
      wout[(size_t)c * 16 + r] = wv[r] * inv;
      iout[(size_t)c * 16 + r] = topi[r];
    }
  }
}

// ---- Time-delay aggregation: outT[c][t] = sum_i w_i * v[min(idx_i+t,L-1)] -
__global__ __launch_bounds__(256) void agg_kernel(const float* __restrict__ vT,
                                                  const float* __restrict__ wbuf,
                                                  const int* __restrict__ ibuf,
                                                  float* __restrict__ outT) {
  __shared__ float v2[2 * LSEQ];     // clamped extension: v2[j>=1024] = v[1023]
  __shared__ float ws[TOPK];
  __shared__ int   is[TOPK];
  int c = blockIdx.x, tid = threadIdx.x;
  const float* v = vT + (size_t)c * LSEQ;
  float last = v[LSEQ - 1];
  float4 vv = ((const float4*)v)[tid];
  ((float4*)v2)[tid]       = vv;
  ((float4*)v2)[tid + 256] = make_float4(last, last, last, last);
  if (tid < TOPK) { ws[tid] = wbuf[(size_t)c * 16 + tid]; is[tid] = ibuf[(size_t)c * 16 + tid]; }
  __syncthreads();
  float a0 = 0.f, a1 = 0.f, a2 = 0.f, a3 = 0.f;
#pragma unroll
  for (int i = 0; i < TOPK; ++i) {
    float wi = ws[i]; int di = is[i];
    a0 += wi * v2[di + tid];
    a1 += wi * v2[di + tid + 256];
    a2 += wi * v2[di + tid + 512];
    a3 += wi * v2[di + tid + 768];
  }
  float* o = outT + (size_t)c * LSEQ + tid;
  o[0] = a0; o[256] = a1; o[512] = a2; o[768] = a3;
}

extern "C" void kernel_launch(void* const* d_in, const int* in_sizes, int n_in,
                              void* d_out, int out_size, void* d_ws, size_t ws_size,
                              hipStream_t stream) {
  const float* Q = (const float*)d_in[0];
  const float* K = (const float*)d_in[1];
  const float* V = (const float*)d_in[2];
  float* out = (float*)d_out;
  float* ws  = (float*)d_ws;
  // ws layout (floats): bufA[8192*1024] | bufB[8192*1024] | w[8192*16] | idx[8192*16]
  float* bufA = ws;
  float* bufB = ws + (size_t)NCH * LSEQ;
  float* wbuf = ws + (size_t)2 * NCH * LSEQ;
  int*   ibuf = (int*)(wbuf + (size_t)NCH * 16);

  dim3 tb(32, 8);
  transpose_rc<<<dim3(16, 32, 16), tb, 0, stream>>>(Q, bufA, 1024, 512);  // qT
  transpose_rc<<<dim3(16, 32, 16), tb, 0, stream>>>(K, bufB, 1024, 512);  // kT
  corr_topk_kernel<<<NCH / 4, 256, 0, stream>>>(bufA, bufB, wbuf, ibuf);
  transpose_rc<<<dim3(16, 32, 16), tb, 0, stream>>>(V, bufA, 1024, 512);  // vT (qT dead)
  agg_kernel<<<NCH, 256, 0, stream>>>(bufA, wbuf, ibuf, bufB);            // outT (kT dead)
  transpose_rc<<<dim3(32, 16, 16), tb, 0, stream>>>(bufB, out, 512, 1024);
}

// Round 6
// 408.199 us; speedup vs baseline: 1.7773x; 1.0054x over previous
//
#include <hip/hip_runtime.h>
#include <float.h>

#define LSEQ 1024
#define NCH  8192   // B*H*d = 16*8*64
#define TOPK 13     // int(2*ln(1024))
#define KPAD 1088   // 1024 + 1024/16 padding (addr(f) = f + (f>>4))

__device__ __forceinline__ float rdlane(float v, unsigned l) {
  return __uint_as_float(__builtin_amdgcn_readlane(__float_as_uint(v), l));
}

// ---- Tiled transpose: in[b][r][c] -> out[b][c][r] -------------------------
__global__ __launch_bounds__(256) void transpose_rc(const float* __restrict__ in,
                                                    float* __restrict__ out,
                                                    int rows, int cols) {
  __shared__ float tile[32][33];
  int b  = blockIdx.z;
  int r0 = blockIdx.y * 32, c0 = blockIdx.x * 32;
  const float* src = in  + (size_t)b * rows * cols;
  float*       dst = out + (size_t)b * rows * cols;
  int tx = threadIdx.x, ty = threadIdx.y;   // block (32,8)
#pragma unroll
  for (int j = 0; j < 32; j += 8)
    tile[ty + j][tx] = src[(size_t)(r0 + ty + j) * cols + (c0 + tx)];
  __syncthreads();
#pragma unroll
  for (int j = 0; j < 32; j += 8)
    dst[(size_t)(c0 + ty + j) * rows + (r0 + tx)] = tile[tx][ty + j];
}

// ---- Merged Q+K transpose (one launch, z in [0,32)) -----------------------
__global__ __launch_bounds__(256) void transpose_qk(const float* __restrict__ Q,
                                                    const float* __restrict__ K,
                                                    float* __restrict__ qT,
                                                    float* __restrict__ kT) {
  __shared__ float tile[32][33];
  int zz = blockIdx.z;
  const float* in  = (zz < 16) ? Q  : K;
  float*       out = (zz < 16) ? qT : kT;
  int b = zz & 15;
  const int rows = 1024, cols = 512;
  int r0 = blockIdx.y * 32, c0 = blockIdx.x * 32;
  const float* src = in  + (size_t)b * rows * cols;
  float*       dst = out + (size_t)b * rows * cols;
  int tx = threadIdx.x, ty = threadIdx.y;
#pragma unroll
  for (int j = 0; j < 32; j += 8)
    tile[ty + j][tx] = src[(size_t)(r0 + ty + j) * cols + (c0 + tx)];
  __syncthreads();
#pragma unroll
  for (int j = 0; j < 32; j += 8)
    dst[(size_t)(c0 + ty + j) * rows + (r0 + tx)] = tile[tx][ty + j];
}

// ---- Fused circular correlation + top-13 + softmax ------------------------
// One wave per channel; lane owns 16 consecutive taus. k in padded LDS
// (addr f+(f>>4), conflict-free b32 — R4 evidence). k window in a mod-32
// circular register buffer, 8-phase-unrolled (static indices, R5). NEW (R6):
// q row preloaded into 16 VGPRs (4x coalesced b128); q[4t..4t+3] broadcast
// from lane t&63 of chunk t>>6 via v_readlane — removes the per-iteration
// uniform global load whose latency doubled R5's VALU time. T-loop unrolled
// so vqs[T] is statically indexed; m-loop kept rolled for I-cache.
__global__ __launch_bounds__(256) void corr_topk_kernel(const float* __restrict__ qT,
                                                        const float* __restrict__ kT,
                                                        float* __restrict__ wout,
                                                        int* __restrict__ iout) {
  __shared__ float kpad[4][KPAD];
  int wave = threadIdx.x >> 6, lane = threadIdx.x & 63;
  int c = blockIdx.x * 4 + wave;
  float* kp = kpad[wave];

  // Stage k into padded LDS. Own wave's data only -> no __syncthreads.
  {
    const float4* k4 = (const float4*)(kT + (size_t)c * LSEQ);
#pragma unroll
    for (int j = 0; j < 4; ++j) {
      int q = lane + 64 * j;          // quad index
      float4 kv = k4[q];
      int a = 4 * q + (q >> 2);       // padded addr (quad never crosses a pad)
      kp[a] = kv.x; kp[a + 1] = kv.y; kp[a + 2] = kv.z; kp[a + 3] = kv.w;
    }
  }
  // Preload whole q row into registers: chunk j, lane l holds q[256j+4l..+3].
  const float4* q4r = (const float4*)(qT + (size_t)c * LSEQ);
  float4 vqs[4];
#pragma unroll
  for (int j = 0; j < 4; ++j) vqs[j] = q4r[lane + 64 * j];

  // cb[(g + 4t) & 31] holds k[(F + g + 4t) & 1023]; F = 1008 - 16*lane.
  int F = 1008 - 16 * lane;
  float cb[32];
#pragma unroll
  for (int g = 0; g < 20; ++g) {
    int gg = (F + g) & 1023;
    cb[g] = kp[gg + (gg >> 4)];
  }
  float acc[16];
#pragma unroll
  for (int i = 0; i < 16; ++i) acc[i] = 0.f;

  int gq = (F + 20) & 1023;           // next k element to load (use, then +=4)

#pragma unroll
  for (int T = 0; T < 4; ++T) {       // UNROLLED: vqs[T] statically indexed
    float4 VQ = vqs[T];
#pragma unroll 1
    for (int m = 0; m < 8; ++m) {     // rolled: keeps body ~5KB in L1I
      unsigned lb = (unsigned)(m * 8);  // uniform -> SGPR
#pragma unroll
      for (int p = 0; p < 8; ++p) {   // cb phase period (4*8 == 32)
        float qx = rdlane(VQ.x, lb + p);
        float qy = rdlane(VQ.y, lb + p);
        float qz = rdlane(VQ.z, lb + p);
        float qw = rdlane(VQ.w, lb + p);
#pragma unroll
        for (int i = 0; i < 16; ++i) {
          acc[i] += qx * cb[(4 * p + 16 - i) & 31];
          acc[i] += qy * cb[(4 * p + 17 - i) & 31];
          acc[i] += qz * cb[(4 * p + 18 - i) & 31];
          acc[i] += qw * cb[(4 * p + 19 - i) & 31];
        }
        int a0 = gq + (gq >> 4);      // quad never crosses a pad (gq%4==0)
        cb[(4 * p + 20) & 31] = kp[a0];
        cb[(4 * p + 21) & 31] = kp[a0 + 1];
        cb[(4 * p + 22) & 31] = kp[a0 + 2];
        cb[(4 * p + 23) & 31] = kp[a0 + 3];
        gq = (gq + 4) & 1023;
      }
    }
  }

  // ---- in-register top-13 (ties -> lowest index, matching lax.top_k) ----
  float topv[TOPK]; int topi[TOPK];
  for (int r = 0; r < TOPK; ++r) {
    float m = -FLT_MAX; int mi = 0x7fffffff;
#pragma unroll
    for (int j = 0; j < 16; ++j) {
      int idx = 16 * lane + j;
      if (acc[j] > m || (acc[j] == m && idx < mi)) { m = acc[j]; mi = idx; }
    }
#pragma unroll
    for (int off = 32; off >= 1; off >>= 1) {
      float om = __shfl_xor(m, off);
      int   oi = __shfl_xor(mi, off);
      if (om > m || (om == m && oi < mi)) { m = om; mi = oi; }
    }
    topv[r] = m; topi[r] = mi;
#pragma unroll
    for (int j = 0; j < 16; ++j)        // static-indexed knockout
      acc[j] = (16 * lane + j == mi) ? -FLT_MAX : acc[j];
  }
  float mx = topv[0];
  float wv[TOPK]; float wsum = 0.f;
#pragma unroll
  for (int r = 0; r < TOPK; ++r) { wv[r] = __expf(topv[r] - mx); wsum += wv[r]; }
  float inv = 1.0f / wsum;
  if (lane == 0) {
#pragma unroll
    for (int r = 0; r < TOPK; ++r) {
      wout[(size_t)c * 16 + r] = wv[r] * inv;
      iout[(size_t)c * 16 + r] = topi[r];
    }
  }
}

// ---- Time-delay aggregation: outT[c][t] = sum_i w_i * v[min(idx_i+t,L-1)] -
__global__ __launch_bounds__(256) void agg_kernel(const float* __restrict__ vT,
                                                  const float* __restrict__ wbuf,
                                                  const int* __restrict__ ibuf,
                                                  float* __restrict__ outT) {
  __shared__ float v2[2 * LSEQ];     // clamped extension: v2[j>=1024] = v[1023]
  __shared__ float ws[TOPK];
  __shared__ int   is[TOPK];
  int c = blockIdx.x, tid = threadIdx.x;
  const float* v = vT + (size_t)c * LSEQ;
  float last = v[LSEQ - 1];
  float4 vv = ((const float4*)v)[tid];
  ((float4*)v2)[tid]       = vv;
  ((float4*)v2)[tid + 256] = make_float4(last, last, last, last);
  if (tid < TOPK) { ws[tid] = wbuf[(size_t)c * 16 + tid]; is[tid] = ibuf[(size_t)c * 16 + tid]; }
  __syncthreads();
  float a0 = 0.f, a1 = 0.f, a2 = 0.f, a3 = 0.f;
#pragma unroll
  for (int i = 0; i < TOPK; ++i) {
    float wi = ws[i]; int di = is[i];
    a0 += wi * v2[di + tid];
    a1 += wi * v2[di + tid + 256];
    a2 += wi * v2[di + tid + 512];
    a3 += wi * v2[di + tid + 768];
  }
  float* o = outT + (size_t)c * LSEQ + tid;
  o[0] = a0; o[256] = a1; o[512] = a2; o[768] = a3;
}

extern "C" void kernel_launch(void* const* d_in, const int* in_sizes, int n_in,
                              void* d_out, int out_size, void* d_ws, size_t ws_size,
                              hipStream_t stream) {
  const float* Q = (const float*)d_in[0];
  const float* K = (const float*)d_in[1];
  const float* V = (const float*)d_in[2];
  float* out = (float*)d_out;
  float* ws  = (float*)d_ws;
  // ws layout (floats): bufA[8192*1024] | bufB[8192*1024] | w[8192*16] | idx[8192*16]
  float* bufA = ws;
  float* bufB = ws + (size_t)NCH * LSEQ;
  float* wbuf = ws + (size_t)2 * NCH * LSEQ;
  int*   ibuf = (int*)(wbuf + (size_t)NCH * 16);

  dim3 tb(32, 8);
  transpose_qk<<<dim3(16, 32, 32), tb, 0, stream>>>(Q, K, bufA, bufB);    // qT, kT
  corr_topk_kernel<<<NCH / 4, 256, 0, stream>>>(bufA, bufB, wbuf, ibuf);
  transpose_rc<<<dim3(16, 32, 16), tb, 0, stream>>>(V, bufA, 1024, 512);  // vT (qT dead)
  agg_kernel<<<NCH, 256, 0, stream>>>(bufA, wbuf, ibuf, bufB);            // outT (kT dead)
  transpose_rc<<<dim3(32, 16, 16), tb, 0, stream>>>(bufB, out, 512, 1024);
}